// Round 1
// baseline (911.835 us; speedup 1.0000x reference)
//
#include <hip/hip_runtime.h>
#include <hip/hip_bf16.h>

// Problem constants (AWQLinear): x[2,2048,4096] f32, q_weight[11008,4096] i32 in [0,16),
// scales[11008,128] f32, input_scale[4096] f32, bias[11008] f32 -> out[2,2048,11008] f32.
#define IN_F   4096
#define OUT_F  11008
#define MROWS  4096      // B*S
#define QBLK   32        // AWQ block == BK of the GEMM (one scale per K-tile row)

typedef __attribute__((ext_vector_type(8))) short   bf16x8;  // 8 bf16 in 4 VGPRs (guide-verified type)
typedef __attribute__((ext_vector_type(8))) unsigned short ushortx8;
typedef __attribute__((ext_vector_type(4))) float   f32x4;

// fp32 -> bf16 round-to-nearest-even (manual: avoids header union/ctor issues)
static __device__ __forceinline__ unsigned short f2bf(float f) {
    unsigned int u = __builtin_bit_cast(unsigned int, f);
    u += 0x7fffu + ((u >> 16) & 1u);
    return (unsigned short)(u >> 16);
}

// async global->LDS, 16B per lane. HW dest = wave-uniform base + lane*16,
// so the LDS layout below is lane-contiguous (NO padding) by construction.
static __device__ __forceinline__ void gl_lds16(const void* g, void* l) {
    __builtin_amdgcn_global_load_lds((const __attribute__((address_space(1))) void*)g,
                                     (__attribute__((address_space(3))) void*)l,
                                     16, 0, 0);
}

// ---------------- kernel 1: W dequant (int4-as-int32 -> bf16), [OUT_F][IN_F] ----------------
__global__ __launch_bounds__(256) void dequant_w_kernel(const int* __restrict__ q,
                                                        const float* __restrict__ scales,
                                                        unsigned short* __restrict__ W) {
    const size_t base = ((size_t)blockIdx.x * 256 + threadIdx.x) * 8;   // 8 elems/thread
    const int4 q0 = *(const int4*)(q + base);
    const int4 q1 = *(const int4*)(q + base + 4);
    const int n = (int)(base >> 12);          // /IN_F
    const int k = (int)(base & (IN_F - 1));
    const float s = scales[(n << 7) | (k >> 5)];   // 8 consecutive k share one 32-block
    ushortx8 v;
    v[0] = f2bf(((float)q0.x - 8.0f) * s);
    v[1] = f2bf(((float)q0.y - 8.0f) * s);
    v[2] = f2bf(((float)q0.z - 8.0f) * s);
    v[3] = f2bf(((float)q0.w - 8.0f) * s);
    v[4] = f2bf(((float)q1.x - 8.0f) * s);
    v[5] = f2bf(((float)q1.y - 8.0f) * s);
    v[6] = f2bf(((float)q1.z - 8.0f) * s);
    v[7] = f2bf(((float)q1.w - 8.0f) * s);
    *(ushortx8*)(W + base) = v;
}

// ---------------- kernel 2: x / input_scale -> bf16, [MROWS][IN_F] ----------------
__global__ __launch_bounds__(256) void scale_x_kernel(const float* __restrict__ x,
                                                      const float* __restrict__ alpha,
                                                      unsigned short* __restrict__ Xs) {
    const size_t base = ((size_t)blockIdx.x * 256 + threadIdx.x) * 8;
    const int k = (int)(base & (IN_F - 1));
    const float4 x0 = *(const float4*)(x + base);
    const float4 x1 = *(const float4*)(x + base + 4);
    const float4 a0 = *(const float4*)(alpha + k);
    const float4 a1 = *(const float4*)(alpha + k + 4);
    ushortx8 v;
    v[0] = f2bf(x0.x / a0.x);
    v[1] = f2bf(x0.y / a0.y);
    v[2] = f2bf(x0.z / a0.z);
    v[3] = f2bf(x0.w / a0.w);
    v[4] = f2bf(x1.x / a1.x);
    v[5] = f2bf(x1.y / a1.y);
    v[6] = f2bf(x1.z / a1.z);
    v[7] = f2bf(x1.w / a1.w);
    *(ushortx8*)(Xs + base) = v;
}

// ---------------- kernel 3: C[M][N] = A[M][K] * W[N][K]^T + bias  (m97 structure) ----------------
// 128x128 tile, BK=32, 256 thr = 4 waves, each wave 64x64 (4x4 tiles of 16x16x32 bf16 MFMA).
__global__ __launch_bounds__(256) void gemm_bt_kernel(const unsigned short* __restrict__ A,
                                                      const unsigned short* __restrict__ Bw,
                                                      const float* __restrict__ bias,
                                                      float* __restrict__ C) {
    // Lane-contiguous LDS (global_load_lds requirement): [128][32] bf16, 64 B/row, no pad.
    __shared__ __align__(16) unsigned short As[128 * 32];
    __shared__ __align__(16) unsigned short Bs[128 * 32];

    const int tid  = threadIdx.x;
    const int wave = tid >> 6;
    const int lane = tid & 63;
    const int m0 = blockIdx.y << 7;
    const int n0 = blockIdx.x << 7;
    const int wm = (wave & 1) << 6;    // wave's 64-row quadrant
    const int wn = (wave >> 1) << 6;   // wave's 64-col quadrant

    // Staging: each wave fills 2 chunks of 1024 B (16 rows each); lane -> base + lane*16 B.
    const int srow = wave * 32 + (lane >> 2);     // first chunk's tile row
    const int scol = (lane & 3) * 8;              // k offset (8 bf16 = 16 B)
    const unsigned short* gA  = A  + (size_t)(m0 + srow) * IN_F + scol;
    const unsigned short* gB  = Bw + (size_t)(n0 + srow) * IN_F + scol;
    const unsigned short* gA2 = gA + (size_t)16 * IN_F;   // second chunk: +16 rows
    const unsigned short* gB2 = gB + (size_t)16 * IN_F;
    unsigned short* lA = As + wave * 1024 + lane * 8;     // 1024 elems = 2 KiB per wave pair
    unsigned short* lB = Bs + wave * 1024 + lane * 8;

    f32x4 acc[4][4] = {};   // 64 VGPRs of accumulator

    // MFMA fragment addressing (16x16x32): m/n = lane&15, k = (lane>>4)*8 + j
    const int fr = lane & 15;
    const int fk = (lane >> 4) << 3;

    for (int kt = 0; kt < IN_F; kt += QBLK) {
        __syncthreads();                       // prior iter's ds_reads done before overwrite
        gl_lds16(gA  + kt, lA);
        gl_lds16(gA2 + kt, lA + 512);
        gl_lds16(gB  + kt, lB);
        gl_lds16(gB2 + kt, lB + 512);
        __syncthreads();                       // drains vmcnt(0): staging visible

        bf16x8 af[4], bfr[4];
#pragma unroll
        for (int mt = 0; mt < 4; ++mt)
            af[mt] = *(const bf16x8*)(As + (wm + mt * 16 + fr) * 32 + fk);
#pragma unroll
        for (int nt = 0; nt < 4; ++nt)
            bfr[nt] = *(const bf16x8*)(Bs + (wn + nt * 16 + fr) * 32 + fk);
#pragma unroll
        for (int mt = 0; mt < 4; ++mt)
#pragma unroll
            for (int nt = 0; nt < 4; ++nt)
                acc[mt][nt] = __builtin_amdgcn_mfma_f32_16x16x32_bf16(af[mt], bfr[nt],
                                                                      acc[mt][nt], 0, 0, 0);
    }

    // Epilogue: C/D layout col = lane&15, row = (lane>>4)*4 + reg (m89/m91-verified). + bias.
    const int cr = (lane >> 4) << 2;
    const int cc = lane & 15;
#pragma unroll
    for (int nt = 0; nt < 4; ++nt) {
        const int gn = n0 + wn + nt * 16 + cc;
        const float bv = bias[gn];
#pragma unroll
        for (int mt = 0; mt < 4; ++mt) {
            const int gm = m0 + wm + mt * 16 + cr;
            float* cp = C + (size_t)gm * OUT_F + gn;
#pragma unroll
            for (int r = 0; r < 4; ++r)
                cp[(size_t)r * OUT_F] = acc[mt][nt][r] + bv;
        }
    }
}

extern "C" void kernel_launch(void* const* d_in, const int* in_sizes, int n_in,
                              void* d_out, int out_size, void* d_ws, size_t ws_size,
                              hipStream_t stream) {
    const float* x      = (const float*)d_in[0];
    const int*   qw     = (const int*)  d_in[1];
    const float* scales = (const float*)d_in[2];
    const float* alpha  = (const float*)d_in[3];
    const float* bias   = (const float*)d_in[4];
    float* out = (float*)d_out;

    // Workspace layout: W bf16 [OUT_F][IN_F] (90,177,536 B) then Xs bf16 [MROWS][IN_F]
    // (33,554,432 B). Total ~118 MiB — assumed <= ws_size.
    unsigned short* W  = (unsigned short*)d_ws;
    unsigned short* Xs = (unsigned short*)((char*)d_ws + (size_t)OUT_F * IN_F * 2);

    dequant_w_kernel<<<(OUT_F * IN_F) / (8 * 256), 256, 0, stream>>>(qw, scales, W);   // 22016 blocks
    scale_x_kernel <<<(MROWS * IN_F) / (8 * 256), 256, 0, stream>>>(x, alpha, Xs);     // 8192 blocks
    dim3 grid(OUT_F / 128, MROWS / 128);                                               // 86 x 32
    gemm_bt_kernel<<<grid, 256, 0, stream>>>(Xs, W, bias, out);
}

// Round 2
// 778.960 us; speedup vs baseline: 1.1706x; 1.1706x over previous
//
#include <hip/hip_runtime.h>
#include <hip/hip_bf16.h>

// Problem constants (AWQLinear): x[2,2048,4096] f32, q_weight[11008,4096] i32 in [0,16),
// scales[11008,128] f32, input_scale[4096] f32, bias[11008] f32 -> out[2,2048,11008] f32.
#define IN_F   4096
#define OUT_F  11008
#define MROWS  4096      // B*S
#define QBLK   32        // AWQ block == BK of the GEMM (one scale per K-tile row)

typedef __attribute__((ext_vector_type(8))) short   bf16x8;  // 8 bf16 in 4 VGPRs
typedef __attribute__((ext_vector_type(8))) unsigned short ushortx8;
typedef __attribute__((ext_vector_type(4))) float   f32x4;

// fp32 -> bf16 round-to-nearest-even
static __device__ __forceinline__ unsigned short f2bf(float f) {
    unsigned int u = __builtin_bit_cast(unsigned int, f);
    u += 0x7fffu + ((u >> 16) & 1u);
    return (unsigned short)(u >> 16);
}

// async global->LDS, 16B per lane. HW dest = wave-uniform base + lane*16.
static __device__ __forceinline__ void gl_lds16(const void* g, void* l) {
    __builtin_amdgcn_global_load_lds((const __attribute__((address_space(1))) void*)g,
                                     (__attribute__((address_space(3))) void*)l,
                                     16, 0, 0);
}

// ---------------- kernel 1: W dequant (int4-as-int32 -> bf16), [OUT_F][IN_F] ----------------
__global__ __launch_bounds__(256) void dequant_w_kernel(const int* __restrict__ q,
                                                        const float* __restrict__ scales,
                                                        unsigned short* __restrict__ W) {
    const size_t base = ((size_t)blockIdx.x * 256 + threadIdx.x) * 8;   // 8 elems/thread
    const int4 q0 = *(const int4*)(q + base);
    const int4 q1 = *(const int4*)(q + base + 4);
    const int n = (int)(base >> 12);          // /IN_F
    const int k = (int)(base & (IN_F - 1));
    const float s = scales[(n << 7) | (k >> 5)];   // 8 consecutive k share one 32-block
    ushortx8 v;
    v[0] = f2bf(((float)q0.x - 8.0f) * s);
    v[1] = f2bf(((float)q0.y - 8.0f) * s);
    v[2] = f2bf(((float)q0.z - 8.0f) * s);
    v[3] = f2bf(((float)q0.w - 8.0f) * s);
    v[4] = f2bf(((float)q1.x - 8.0f) * s);
    v[5] = f2bf(((float)q1.y - 8.0f) * s);
    v[6] = f2bf(((float)q1.z - 8.0f) * s);
    v[7] = f2bf(((float)q1.w - 8.0f) * s);
    *(ushortx8*)(W + base) = v;
}

// ---------------- kernel 2: x / input_scale -> bf16, [MROWS][IN_F] ----------------
__global__ __launch_bounds__(256) void scale_x_kernel(const float* __restrict__ x,
                                                      const float* __restrict__ alpha,
                                                      unsigned short* __restrict__ Xs) {
    const size_t base = ((size_t)blockIdx.x * 256 + threadIdx.x) * 8;
    const int k = (int)(base & (IN_F - 1));
    const float4 x0 = *(const float4*)(x + base);
    const float4 x1 = *(const float4*)(x + base + 4);
    const float4 a0 = *(const float4*)(alpha + k);
    const float4 a1 = *(const float4*)(alpha + k + 4);
    ushortx8 v;
    v[0] = f2bf(x0.x / a0.x);
    v[1] = f2bf(x0.y / a0.y);
    v[2] = f2bf(x0.z / a0.z);
    v[3] = f2bf(x0.w / a0.w);
    v[4] = f2bf(x1.x / a1.x);
    v[5] = f2bf(x1.y / a1.y);
    v[6] = f2bf(x1.z / a1.z);
    v[7] = f2bf(x1.w / a1.w);
    *(ushortx8*)(Xs + base) = v;
}

// ---------------- kernel 3: C[M][N] = A[M][K] * W[N][K]^T + bias  ----------------
// 128x128 tile, BK=32, 256 thr = 4 waves, each wave 64x64 (4x4 tiles of 16x16x32 bf16 MFMA).
// R1 changes: (a) 1D grid with 32M x 8N group swizzle for L2/L3 locality;
//             (b) LDS chunk-xor swizzle to kill ds_read_b128 bank conflicts.
__global__ __launch_bounds__(256) void gemm_bt_kernel(const unsigned short* __restrict__ A,
                                                      const unsigned short* __restrict__ Bw,
                                                      const float* __restrict__ bias,
                                                      float* __restrict__ C) {
    // Lane-contiguous LDS (global_load_lds requirement): [128][32] bf16, 64 B/row, no pad.
    __shared__ __align__(16) unsigned short As[128 * 32];
    __shared__ __align__(16) unsigned short Bs[128 * 32];

    const int tid  = threadIdx.x;
    const int wave = tid >> 6;
    const int lane = tid & 63;

    // Grid swizzle: groups of 32 M-tiles x 8 N-tiles = 256 blocks.
    // Group footprint: Xs (all M) 33.5 MB + 8 W-tiles 8.4 MB -> W fetched from HBM once.
    const int bid = blockIdx.x;
    int mtile, ntile;
    if (bid < 2560) {                       // 10 full groups of 8 N-tiles
        mtile = bid & 31;
        ntile = ((bid >> 8) << 3) + ((bid >> 5) & 7);
    } else {                                // remainder group: 6 N-tiles
        const int local = bid - 2560;
        mtile = local & 31;
        ntile = 80 + (local >> 5);
    }
    const int m0 = mtile << 7;
    const int n0 = ntile << 7;
    const int wm = (wave & 1) << 6;    // wave's 64-row quadrant
    const int wn = (wave >> 1) << 6;   // wave's 64-col quadrant

    // Staging: wave fills 2 chunks of 1024 B (16 rows each); lane -> base + lane*16 B.
    // LDS row of lane's 16B = wave*32 + (lane>>2); chunk-in-row = lane&3.
    // Swizzle: LDS (row R, chunk c) holds global (row R, chunk c ^ ((R>>1)&3)).
    // (R>>1)&3 == (lane>>3)&3 for both the +0 and +16 row chunks (16/2 = 8 == 0 mod 4).
    const int srow = wave * 32 + (lane >> 2);           // tile row of first chunk
    const int scol = (((lane & 3) ^ ((lane >> 3) & 3)) << 3);   // swizzled k offset (8 bf16)
    const unsigned short* gA  = A  + (size_t)(m0 + srow) * IN_F + scol;
    const unsigned short* gB  = Bw + (size_t)(n0 + srow) * IN_F + scol;
    const unsigned short* gA2 = gA + (size_t)16 * IN_F;   // second chunk: +16 rows
    const unsigned short* gB2 = gB + (size_t)16 * IN_F;
    unsigned short* lA = As + wave * 1024 + lane * 8;
    unsigned short* lB = Bs + wave * 1024 + lane * 8;

    f32x4 acc[4][4] = {};

    // MFMA fragment addressing (16x16x32): m/n = lane&15, k = (lane>>4)*8 + j.
    // Read-side swizzle: chunk position = q ^ ((row>>1)&3); row parity bits come
    // only from fr (wm, mt*16 are 0 mod 4 after >>1), so it's lane-only:
    const int fr = lane & 15;
    const int fkswz = ((((lane >> 4) ^ ((lane >> 1) & 3))) << 3);

    for (int kt = 0; kt < IN_F; kt += QBLK) {
        __syncthreads();                       // prior iter's ds_reads done before overwrite
        gl_lds16(gA  + kt, lA);
        gl_lds16(gA2 + kt, lA + 512);
        gl_lds16(gB  + kt, lB);
        gl_lds16(gB2 + kt, lB + 512);
        __syncthreads();                       // drains vmcnt(0): staging visible

        bf16x8 af[4], bfr[4];
#pragma unroll
        for (int mt = 0; mt < 4; ++mt)
            af[mt] = *(const bf16x8*)(As + (wm + mt * 16 + fr) * 32 + fkswz);
#pragma unroll
        for (int nt = 0; nt < 4; ++nt)
            bfr[nt] = *(const bf16x8*)(Bs + (wn + nt * 16 + fr) * 32 + fkswz);
#pragma unroll
        for (int mt = 0; mt < 4; ++mt)
#pragma unroll
            for (int nt = 0; nt < 4; ++nt)
                acc[mt][nt] = __builtin_amdgcn_mfma_f32_16x16x32_bf16(af[mt], bfr[nt],
                                                                      acc[mt][nt], 0, 0, 0);
    }

    // Epilogue: C/D layout col = lane&15, row = (lane>>4)*4 + reg. + bias.
    const int cr = (lane >> 4) << 2;
    const int cc = lane & 15;
#pragma unroll
    for (int nt = 0; nt < 4; ++nt) {
        const int gn = n0 + wn + nt * 16 + cc;
        const float bv = bias[gn];
#pragma unroll
        for (int mt = 0; mt < 4; ++mt) {
            const int gm = m0 + wm + mt * 16 + cr;
            float* cp = C + (size_t)gm * OUT_F + gn;
#pragma unroll
            for (int r = 0; r < 4; ++r)
                cp[(size_t)r * OUT_F] = acc[mt][nt][r] + bv;
        }
    }
}

extern "C" void kernel_launch(void* const* d_in, const int* in_sizes, int n_in,
                              void* d_out, int out_size, void* d_ws, size_t ws_size,
                              hipStream_t stream) {
    const float* x      = (const float*)d_in[0];
    const int*   qw     = (const int*)  d_in[1];
    const float* scales = (const float*)d_in[2];
    const float* alpha  = (const float*)d_in[3];
    const float* bias   = (const float*)d_in[4];
    float* out = (float*)d_out;

    // Workspace: W bf16 [OUT_F][IN_F] (~86 MiB) then Xs bf16 [MROWS][IN_F] (32 MiB).
    unsigned short* W  = (unsigned short*)d_ws;
    unsigned short* Xs = (unsigned short*)((char*)d_ws + (size_t)OUT_F * IN_F * 2);

    dequant_w_kernel<<<(OUT_F * IN_F) / (8 * 256), 256, 0, stream>>>(qw, scales, W);
    scale_x_kernel <<<(MROWS * IN_F) / (8 * 256), 256, 0, stream>>>(x, alpha, Xs);
    gemm_bt_kernel<<<(OUT_F / 128) * (MROWS / 128), 256, 0, stream>>>(Xs, W, bias, out);
}